// Round 3
// baseline (283.291 us; speedup 1.0000x reference)
//
#include <hip/hip_runtime.h>

// N=262144 sentences, B=16384 bags (uniform 16/bag, contiguous), D=768, C=53
#define SPB 16          // sentences per bag
#define DIM 768
#define NC  53
#define D4  (DIM/4)     // 192 float4 per x row
#define NT  512         // threads per block (8 waves)
#define NW  8
#define KPT 6           // float4 per thread per sentence (192 / 32 lanes)
#define GBAGS 8         // bags per block, processed sequentially

__global__ __launch_bounds__(NT) void bag_attn_v3(
    const float* __restrict__ x,      // [N][D]
    const float* __restrict__ W,      // [C][D]
    const float* __restrict__ bias,   // [C]
    const int*   __restrict__ scope,  // [B+1]
    const int*   __restrict__ query,  // [N]
    float*       __restrict__ out,    // [B][C]
    int num_bags)
{
    const int t = threadIdx.x;
    const int g = t >> 5;          // sentence 0..15
    const int j = t & 31;          // lane within sentence group
    const int w = t >> 6;          // wave 0..7
    const int l = t & 63;          // lane within wave

    __shared__ float4 xbuf[SPB * D4];   // 48 KiB: current bag's x (then reused)
    __shared__ float  att_lds[SPB];

    const float4* W4 = reinterpret_cast<const float4*>(W);

    for (int bb = 0; bb < GBAGS; ++bb) {
        const int b = blockIdx.x * GBAGS + bb;
        if (b >= num_bags) break;
        const int base = scope[b];                 // uniform: 16 sentences

        // ---- stage x[bag] (48 KB contiguous) into LDS, async, no VGPRs ----
        {
            const float* src = x + (size_t)base * DIM;
            #pragma unroll
            for (int k = 0; k < KPT; ++k) {
                const float* gsrc = src + (size_t)(k * NT + t) * 4;   // 16 B/lane
                float4* ldst = xbuf + (k * NT + t);                    // linear
                __builtin_amdgcn_global_load_lds(
                    (const __attribute__((address_space(1))) void*)gsrc,
                    (__attribute__((address_space(3))) void*)ldst,
                    16, 0, 0);
            }
        }
        asm volatile("s_waitcnt vmcnt(0)" ::: "memory");
        __syncthreads();

        // ---- att[g] = <x_g, W[q_g]>; keep x fragments in registers ----
        const int qg = query[base + g];
        const float4* wrow = W4 + (size_t)qg * D4;
        float4 xr[KPT];
        float att = 0.f;
        #pragma unroll
        for (int k = 0; k < KPT; ++k) {
            const float4 xv = xbuf[g * D4 + j + 32 * k];
            const float4 wv = wrow[j + 32 * k];
            xr[k] = xv;
            att += xv.x * wv.x + xv.y * wv.y + xv.z * wv.z + xv.w * wv.w;
        }
        #pragma unroll
        for (int m = 16; m >= 1; m >>= 1)     // reduce within 32-lane group
            att += __shfl_xor(att, m, 64);
        if (j == 0) att_lds[g] = att;
        __syncthreads();

        // ---- softmax over 16 scores (redundant per thread) ----
        float mx = att_lds[0];
        #pragma unroll
        for (int i = 1; i < SPB; ++i) mx = fmaxf(mx, att_lds[i]);
        float z = 0.f;
        #pragma unroll
        for (int i = 0; i < SPB; ++i) z += __expf(att_lds[i] - mx);
        const float wgt = __expf(att - mx) / z;

        // ---- weighted x back into LDS in place ----
        #pragma unroll
        for (int k = 0; k < KPT; ++k) {
            float4 v = xr[k];
            v.x *= wgt; v.y *= wgt; v.z *= wgt; v.w *= wgt;
            xbuf[g * D4 + j + 32 * k] = v;
        }
        __syncthreads();

        // ---- reduce 16 rows -> row 0 (repre) ----
        if (t < D4) {
            float4 a = xbuf[t];
            #pragma unroll
            for (int s = 1; s < SPB; ++s) {
                const float4 p = xbuf[s * D4 + t];
                a.x += p.x; a.y += p.y; a.z += p.z; a.w += p.w;
            }
            xbuf[t] = a;
        }
        __syncthreads();

        // ---- logits[c] = <repre, W[c]> + bias[c]; classes split over waves ----
        const float4 rr0 = xbuf[l];
        const float4 rr1 = xbuf[l + 64];
        const float4 rr2 = xbuf[l + 128];
        for (int c = w; c < NC; c += NW) {
            const float4* wc = W4 + (size_t)c * D4;
            const float4 w0 = wc[l], w1 = wc[l + 64], w2 = wc[l + 128];
            float s = rr0.x*w0.x + rr0.y*w0.y + rr0.z*w0.z + rr0.w*w0.w
                    + rr1.x*w1.x + rr1.y*w1.y + rr1.z*w1.z + rr1.w*w1.w
                    + rr2.x*w2.x + rr2.y*w2.y + rr2.z*w2.z + rr2.w*w2.w;
            #pragma unroll
            for (int m = 32; m >= 1; m >>= 1)
                s += __shfl_xor(s, m, 64);
            if (l == 0) out[(size_t)b * NC + c] = s + bias[c];
        }
        __syncthreads();   // protect xbuf before next bag's async stage
    }
}

extern "C" void kernel_launch(void* const* d_in, const int* in_sizes, int n_in,
                              void* d_out, int out_size, void* d_ws, size_t ws_size,
                              hipStream_t stream) {
    const float* x     = (const float*)d_in[0];   // [N][768]
    const float* W     = (const float*)d_in[1];   // [53][768]
    const float* bias  = (const float*)d_in[2];   // [53]
    const int*   scope = (const int*)d_in[3];     // [B+1]
    const int*   query = (const int*)d_in[4];     // [N]
    float* out = (float*)d_out;                   // [B][53]

    const int num_bags = in_sizes[3] - 1;         // 16384
    const int grid = (num_bags + GBAGS - 1) / GBAGS;

    bag_attn_v3<<<grid, NT, 0, stream>>>(x, W, bias, scope, query, out, num_bags);
}

// Round 4
// 216.674 us; speedup vs baseline: 1.3075x; 1.3075x over previous
//
#include <hip/hip_runtime.h>

// N=262144 sentences, B=16384 bags (uniform 16/bag, contiguous), D=768, C=53
#define SPB 16
#define DIM 768
#define NC  53
#define D4  (DIM/4)       // 192 float4 per row
#define NT  512           // 8 waves
#define NW  8
#define KPT 6             // float4 per thread per sentence (192 / 32 lanes)
#define GBAGS 8           // bags per block (batched matvec)
#define RSTRIDE 194       // repre row stride in float4 (194*4=776 words, 776%32=8 -> bank-floor)

__global__ __launch_bounds__(NT) void bag_attn_v4(
    const float* __restrict__ x,      // [N][D]
    const float* __restrict__ W,      // [C][D]
    const float* __restrict__ bias,   // [C]
    const int*   __restrict__ scope,  // [B+1]
    const int*   __restrict__ query,  // [N]
    float*       __restrict__ out,    // [B][C]
    int num_bags)
{
    const int t = threadIdx.x;
    const int g = t >> 5;          // sentence 0..15
    const int j = t & 31;          // lane within sentence group
    const int w = t >> 6;          // wave 0..7
    const int l = t & 63;          // lane within wave

    __shared__ float4 part[NW][D4];              // 24 KiB (per-wave partials)
    __shared__ float4 repre[GBAGS * RSTRIDE];    // 24.8 KiB (8 bag reps, padded)
    __shared__ float  att_lds[SPB];

    const float4* x4 = reinterpret_cast<const float4*>(x);
    const float4* W4 = reinterpret_cast<const float4*>(W);

    for (int bb = 0; bb < GBAGS; ++bb) {
        const int b = blockIdx.x * GBAGS + bb;
        if (b >= num_bags) break;                // uniform per block
        const int base = scope[b];               // 16 sentences, contiguous

        // ---- att[g] = <x_g, W[q_g]>; x fragments stay in registers ----
        const int qg = query[base + g];
        const float4* xrow = x4 + (size_t)(base + g) * D4;
        const float4* wrow = W4 + (size_t)qg * D4;
        float4 xr[KPT];
        float att = 0.f;
        #pragma unroll
        for (int k = 0; k < KPT; ++k) {
            const float4 xv = xrow[j + 32 * k];
            const float4 wv = wrow[j + 32 * k];
            xr[k] = xv;
            att += xv.x * wv.x + xv.y * wv.y + xv.z * wv.z + xv.w * wv.w;
        }
        #pragma unroll
        for (int m = 16; m >= 1; m >>= 1)        // reduce within 32-lane group
            att += __shfl_xor(att, m, 64);
        if (j == 0) att_lds[g] = att;
        __syncthreads();                         // (A)

        // ---- softmax over 16 scores (vectorized LDS read, redundant) ----
        const float4* a4 = reinterpret_cast<const float4*>(att_lds);
        const float4 A0 = a4[0], A1 = a4[1], A2 = a4[2], A3 = a4[3];
        float mx = fmaxf(fmaxf(fmaxf(A0.x, A0.y), fmaxf(A0.z, A0.w)),
                  fmaxf(fmaxf(fmaxf(A1.x, A1.y), fmaxf(A1.z, A1.w)),
                  fmaxf(fmaxf(fmaxf(A2.x, A2.y), fmaxf(A2.z, A2.w)),
                        fmaxf(fmaxf(A3.x, A3.y), fmaxf(A3.z, A3.w)))));
        float z = __expf(A0.x-mx)+__expf(A0.y-mx)+__expf(A0.z-mx)+__expf(A0.w-mx)
                + __expf(A1.x-mx)+__expf(A1.y-mx)+__expf(A1.z-mx)+__expf(A1.w-mx)
                + __expf(A2.x-mx)+__expf(A2.y-mx)+__expf(A2.z-mx)+__expf(A2.w-mx)
                + __expf(A3.x-mx)+__expf(A3.y-mx)+__expf(A3.z-mx)+__expf(A3.w-mx);
        const float wgt = __expf(att - mx) / z;

        // ---- weighted x, fold the wave's 2 sentences via xor-32 ----
        #pragma unroll
        for (int k = 0; k < KPT; ++k) {
            float a0 = wgt * xr[k].x, a1 = wgt * xr[k].y,
                  a2 = wgt * xr[k].z, a3 = wgt * xr[k].w;
            a0 += __shfl_xor(a0, 32, 64); a1 += __shfl_xor(a1, 32, 64);
            a2 += __shfl_xor(a2, 32, 64); a3 += __shfl_xor(a3, 32, 64);
            xr[k] = make_float4(a0, a1, a2, a3);
        }
        if (l < 32) {
            #pragma unroll
            for (int k = 0; k < KPT; ++k)
                part[w][l + 32 * k] = xr[k];     // conflict-free b128 writes
        }
        __syncthreads();                         // (B)

        // ---- combine 8 wave-partials -> repre[bb] (threads 0..191) ----
        if (t < D4) {
            float4 acc = part[0][t];
            #pragma unroll
            for (int r = 1; r < NW; ++r) {
                const float4 p = part[r][t];
                acc.x += p.x; acc.y += p.y; acc.z += p.z; acc.w += p.w;
            }
            repre[bb * RSTRIDE + t] = acc;
        }
        // no barrier: next iteration's (A) orders combine-reads vs part-writes
    }
    __syncthreads();                             // repre visible to all

    // ---- batched matvec: logits[8 bags][53] with W read ONCE per block ----
    const int bb2 = l >> 3;          // bag 0..7
    const int dg  = l & 7;           // dim group 0..7 (interleaved float4s)
    const int b0  = blockIdx.x * GBAGS;

    float acc[7] = {0.f, 0.f, 0.f, 0.f, 0.f, 0.f, 0.f};
    #pragma unroll
    for (int s = 0; s < 24; ++s) {
        const float4 r4 = repre[bb2 * RSTRIDE + (s * 8 + dg)];
        #pragma unroll
        for (int i = 0; i < 7; ++i) {
            const int c = w + 8 * i;             // wave-uniform
            if (c < NC) {
                const float4 wv = W4[(size_t)c * D4 + s * 8 + dg];
                acc[i] += r4.x * wv.x + r4.y * wv.y + r4.z * wv.z + r4.w * wv.w;
            }
        }
    }
    #pragma unroll
    for (int i = 0; i < 7; ++i) {
        const int c = w + 8 * i;
        if (c < NC) {
            float v = acc[i];
            v += __shfl_xor(v, 1, 64);           // reduce over the 8 dim groups
            v += __shfl_xor(v, 2, 64);
            v += __shfl_xor(v, 4, 64);
            if (dg == 0 && (b0 + bb2) < num_bags)
                out[(size_t)(b0 + bb2) * NC + c] = v + bias[c];
        }
    }
}

extern "C" void kernel_launch(void* const* d_in, const int* in_sizes, int n_in,
                              void* d_out, int out_size, void* d_ws, size_t ws_size,
                              hipStream_t stream) {
    const float* x     = (const float*)d_in[0];   // [N][768]
    const float* W     = (const float*)d_in[1];   // [53][768]
    const float* bias  = (const float*)d_in[2];   // [53]
    const int*   scope = (const int*)d_in[3];     // [B+1]
    const int*   query = (const int*)d_in[4];     // [N]
    float* out = (float*)d_out;                   // [B][53]

    const int num_bags = in_sizes[3] - 1;         // 16384
    const int grid = (num_bags + GBAGS - 1) / GBAGS;

    bag_attn_v4<<<grid, NT, 0, stream>>>(x, W, bias, scope, query, out, num_bags);
}

// Round 5
// 202.817 us; speedup vs baseline: 1.3968x; 1.0683x over previous
//
#include <hip/hip_runtime.h>

// N=262144 sentences (uniform 16/bag, contiguous bags), D=768, C=53
// Reformulation: Y = X * W^T  [N x 53] via bf16 MFMA;
//   att_s = Y[s][q_s]; logits[bag] = sum_s softmax(att)_s * Y[s][:] + bias
#define DIM    768
#define NC     53
#define NCP    64        // classes padded to 4 MFMA n-tiles
#define MTB    256       // sentences per block (= 16 bags)
#define NTH    512       // 8 waves
#define KSTEP  32
#define NSTEPS 24        // 768 / 32
#define APAD   40        // padded LDS row length (bf16 elems); 80 B rows -> ~2-way banks

typedef __attribute__((ext_vector_type(8))) short short8;
typedef __attribute__((ext_vector_type(4))) float f32x4;

static __device__ inline unsigned short f2bf(float f) {
    unsigned u = __float_as_uint(f);
    u += 0x7fff + ((u >> 16) & 1);           // round-to-nearest-even
    return (unsigned short)(u >> 16);
}

// ---- kernel 1: W fp32 [53][768] -> bf16 [64][768] in d_ws (rows 53..63 = 0) ----
__global__ void wconv_kernel(const float* __restrict__ W, unsigned short* __restrict__ Wt) {
    const int idx = blockIdx.x * 256 + threadIdx.x;
    if (idx >= NCP * DIM) return;
    const int c = idx / DIM, k = idx - c * DIM;
    const float v = (c < NC) ? W[c * DIM + k] : 0.f;
    Wt[idx] = f2bf(v);
}

static __device__ inline void cvt_store(unsigned short* dst, const float4* r) {
    union { short8 v; unsigned short u[8]; } a, b;
    a.u[0]=f2bf(r[0].x); a.u[1]=f2bf(r[0].y); a.u[2]=f2bf(r[0].z); a.u[3]=f2bf(r[0].w);
    a.u[4]=f2bf(r[1].x); a.u[5]=f2bf(r[1].y); a.u[6]=f2bf(r[1].z); a.u[7]=f2bf(r[1].w);
    b.u[0]=f2bf(r[2].x); b.u[1]=f2bf(r[2].y); b.u[2]=f2bf(r[2].z); b.u[3]=f2bf(r[2].w);
    b.u[4]=f2bf(r[3].x); b.u[5]=f2bf(r[3].y); b.u[6]=f2bf(r[3].z); b.u[7]=f2bf(r[3].w);
    *reinterpret_cast<short8*>(dst)     = a.v;
    *reinterpret_cast<short8*>(dst + 8) = b.v;
}

__global__ __launch_bounds__(NTH) void bag_attn_mfma(
    const float* __restrict__ x,              // [N][768] fp32
    const unsigned short* __restrict__ Wt,    // [64][768] bf16 (d_ws)
    const float* __restrict__ bias,           // [53]
    const int*   __restrict__ query,          // [N]
    float*       __restrict__ out)            // [B][53]
{
    __shared__ __align__(16) unsigned short Ab[2][MTB * APAD];  // 40 KiB
    __shared__ float att_sm[16][16];
    __shared__ int   qbuf[MTB];

    const int t   = threadIdx.x;
    const int w   = t >> 6;        // wave 0..7 -> rows 32w..32w+31 (bags 2w,2w+1)
    const int l   = t & 63;
    const int blk = blockIdx.x;
    const int row_g = blk * MTB;

    if (t < MTB) qbuf[t] = query[row_g + t];

    // staging map: thread t -> row t>>1, k-half t&1 (16 fp32 = 4 float4)
    const int srow  = t >> 1;
    const int shalf = t & 1;
    const float4* x4 = reinterpret_cast<const float4*>(x)
                     + (size_t)(row_g + srow) * (DIM / 4) + shalf * 4;
    unsigned short* dst0 = &Ab[0][srow * APAD + shalf * 16];
    unsigned short* dst1 = &Ab[1][srow * APAD + shalf * 16];

    f32x4 acc[2][4];
    #pragma unroll
    for (int mi = 0; mi < 2; ++mi)
        #pragma unroll
        for (int ni = 0; ni < 4; ++ni)
            acc[mi][ni] = (f32x4){0.f, 0.f, 0.f, 0.f};

    float4 rA[4], rB[4];
    #pragma unroll
    for (int m = 0; m < 4; ++m) rA[m] = x4[0 * 8 + m];   // tile 0
    #pragma unroll
    for (int m = 0; m < 4; ++m) rB[m] = x4[1 * 8 + m];   // tile 1
    cvt_store(dst0, rA);                                  // tile 0 -> buf0
    __syncthreads();

#define COMPUTE(p, kk)                                                         \
    {                                                                          \
        short8 bfr[4];                                                         \
        _Pragma("unroll")                                                      \
        for (int ni = 0; ni < 4; ++ni)                                         \
            bfr[ni] = *reinterpret_cast<const short8*>(                        \
                Wt + ((16 * ni + (l & 15)) * DIM + (kk) * KSTEP + (l >> 4) * 8)); \
        short8 afr[2];                                                         \
        _Pragma("unroll")                                                      \
        for (int mi = 0; mi < 2; ++mi)                                         \
            afr[mi] = *reinterpret_cast<const short8*>(                        \
                &Ab[p][(32 * w + 16 * mi + (l & 15)) * APAD + (l >> 4) * 8]);  \
        _Pragma("unroll")                                                      \
        for (int mi = 0; mi < 2; ++mi)                                         \
            _Pragma("unroll")                                                  \
            for (int ni = 0; ni < 4; ++ni)                                     \
                acc[mi][ni] = __builtin_amdgcn_mfma_f32_16x16x32_bf16(         \
                    afr[mi], bfr[ni], acc[mi][ni], 0, 0, 0);                   \
    }

    for (int kk = 0; kk < NSTEPS; kk += 2) {
        // even phase: compute buf0 = tile kk; stage tile kk+1 -> buf1
        if (kk + 2 < NSTEPS) {
            #pragma unroll
            for (int m = 0; m < 4; ++m) rA[m] = x4[(kk + 2) * 8 + m];
        }
        COMPUTE(0, kk);
        cvt_store(dst1, rB);            // waits on rB's loads (tile kk+1)
        __syncthreads();
        // odd phase: compute buf1 = tile kk+1; stage tile kk+2 -> buf0
        if (kk + 3 < NSTEPS) {
            #pragma unroll
            for (int m = 0; m < 4; ++m) rB[m] = x4[(kk + 3) * 8 + m];
        }
        COMPUTE(1, kk + 1);
        if (kk + 2 < NSTEPS) {
            cvt_store(dst0, rA);        // tile kk+2 -> buf0
            __syncthreads();
        }
    }
#undef COMPUTE

    // ---- epilogue: att extraction from acc fragments ----
    // D-layout (16x16x32, verified): col = lane&15, row = (lane>>4)*4 + reg
    #pragma unroll
    for (int mi = 0; mi < 2; ++mi) {
        #pragma unroll
        for (int r = 0; r < 4; ++r) {
            const int s_loc = ((l >> 4) << 2) + r;
            const int q = qbuf[32 * w + 16 * mi + s_loc];
            if ((q & 15) == (l & 15)) {       // exactly one lane per row matches
                float v = acc[mi][0][r];
                if ((q >> 4) == 1) v = acc[mi][1][r];
                if ((q >> 4) == 2) v = acc[mi][2][r];
                if ((q >> 4) == 3) v = acc[mi][3][r];
                att_sm[2 * w + mi][s_loc] = v;
            }
        }
    }
    __syncthreads();

    // ---- per-bag softmax + weighted logits (bags are wave-local) ----
    #pragma unroll
    for (int mi = 0; mi < 2; ++mi) {
        const int bag = 2 * w + mi;
        const float4* a4 = reinterpret_cast<const float4*>(&att_sm[bag][0]);
        const float4 A0 = a4[0], A1 = a4[1], A2 = a4[2], A3 = a4[3];
        float mx = fmaxf(fmaxf(fmaxf(A0.x, A0.y), fmaxf(A0.z, A0.w)),
                  fmaxf(fmaxf(fmaxf(A1.x, A1.y), fmaxf(A1.z, A1.w)),
                  fmaxf(fmaxf(fmaxf(A2.x, A2.y), fmaxf(A2.z, A2.w)),
                        fmaxf(fmaxf(A3.x, A3.y), fmaxf(A3.z, A3.w)))));
        float zz = __expf(A0.x-mx)+__expf(A0.y-mx)+__expf(A0.z-mx)+__expf(A0.w-mx)
                 + __expf(A1.x-mx)+__expf(A1.y-mx)+__expf(A1.z-mx)+__expf(A1.w-mx)
                 + __expf(A2.x-mx)+__expf(A2.y-mx)+__expf(A2.z-mx)+__expf(A2.w-mx)
                 + __expf(A3.x-mx)+__expf(A3.y-mx)+__expf(A3.z-mx)+__expf(A3.w-mx);
        const float inv = 1.f / zz;
        const int grp = l >> 4;
        float4 As = A0;
        if (grp == 1) As = A1;
        if (grp == 2) As = A2;
        if (grp == 3) As = A3;
        const float w0 = __expf(As.x - mx) * inv;
        const float w1 = __expf(As.y - mx) * inv;
        const float w2 = __expf(As.z - mx) * inv;
        const float w3 = __expf(As.w - mx) * inv;
        #pragma unroll
        for (int ni = 0; ni < 4; ++ni) {
            float p = w0 * acc[mi][ni][0] + w1 * acc[mi][ni][1]
                    + w2 * acc[mi][ni][2] + w3 * acc[mi][ni][3];
            p += __shfl_xor(p, 16, 64);     // reduce the 4 row-groups
            p += __shfl_xor(p, 32, 64);
            if (l < 16) {
                const int c = 16 * ni + l;
                if (c < NC)
                    out[(size_t)(blk * 16 + bag) * NC + c] = p + bias[c];
            }
        }
    }
}

extern "C" void kernel_launch(void* const* d_in, const int* in_sizes, int n_in,
                              void* d_out, int out_size, void* d_ws, size_t ws_size,
                              hipStream_t stream) {
    const float* x     = (const float*)d_in[0];   // [N][768]
    const float* W     = (const float*)d_in[1];   // [53][768]
    const float* bias  = (const float*)d_in[2];   // [53]
    const int*   query = (const int*)d_in[4];     // [N]
    float* out = (float*)d_out;                   // [B][53]

    unsigned short* Wt = (unsigned short*)d_ws;   // needs 64*768*2 = 96 KiB

    const int nrows  = in_sizes[0] / DIM;         // 262144
    const int nblk   = nrows / MTB;               // 1024

    wconv_kernel<<<(NCP * DIM + 255) / 256, 256, 0, stream>>>(W, Wt);
    bag_attn_mfma<<<nblk, NTH, 0, stream>>>(x, Wt, bias, query, out);
}